// Round 7
// baseline (595.851 us; speedup 1.0000x reference)
//
#include <hip/hip_runtime.h>
#include <hip/hip_bf16.h>

typedef __bf16 bf16_t;
typedef __bf16 bf16x8 __attribute__((ext_vector_type(8)));
typedef __bf16 bf16x4 __attribute__((ext_vector_type(4)));
typedef float f32x4 __attribute__((ext_vector_type(4)));

#define B_DIM 4
#define NQ 2048
#define NK 2048
#define DMODEL 1024
#define NH 8
#define DHEAD 128

#define AS1 __attribute__((address_space(1)))
#define AS3 __attribute__((address_space(3)))

__device__ __forceinline__ void gl_lds16(const void* g, void* l) {
    __builtin_amdgcn_global_load_lds((const AS1 void*)g, (AS3 void*)l, 16, 0, 0);
}

// ---------------------------------------------------------------------------
// fp32 -> bf16 conversion, 6 pairs selected by blockIdx.y
// ---------------------------------------------------------------------------
struct CvtArgs {
    const float* s[6];
    bf16_t* d[6];
    int n[6];
};

__global__ __launch_bounds__(256) void cvt_k(CvtArgs a) {
    const int p = blockIdx.y;
    const float* s = a.s[p];
    bf16_t* d = a.d[p];
    const int n = a.n[p];
    const int stride = gridDim.x * 256 * 8;
    for (int i = (blockIdx.x * 256 + threadIdx.x) * 8; i < n; i += stride) {
        float4 x0 = *(const float4*)(s + i);
        float4 x1 = *(const float4*)(s + i + 4);
        bf16x8 o = {(bf16_t)x0.x, (bf16_t)x0.y, (bf16_t)x0.z, (bf16_t)x0.w,
                    (bf16_t)x1.x, (bf16_t)x1.y, (bf16_t)x1.z, (bf16_t)x1.w};
        *(bf16x8*)(d + i) = o;
    }
}

// ---------------------------------------------------------------------------
// Fused Q/K/V projection: z = blockIdx.z selects (A, W, bias, epilogue).
// C[M,N] = A[M,1024] * W[N,1024]^T + bias.  z==2 scatters to vT.
// ---------------------------------------------------------------------------
__global__ __launch_bounds__(256) void proj_k(
    const bf16_t* Qc, const bf16_t* Kc,
    const bf16_t* Wqc, const bf16_t* Wkc, const bf16_t* Wvc,
    const float* bq, const float* bk, const float* bv,
    bf16_t* qbb, bf16_t* kbb, bf16_t* vT)
{
    const int K = DMODEL, N = DMODEL;
    const int z = blockIdx.z;
    const bf16_t* A  = (z == 0) ? Qc : Kc;
    const bf16_t* Bw = (z == 0) ? Wqc : (z == 1) ? Wkc : Wvc;
    const float* bias = (z == 0) ? bq : (z == 1) ? bk : bv;
    bf16_t* Cb = (z == 0) ? qbb : (z == 1) ? kbb : vT;

    const int tid  = threadIdx.x;
    const int lane = tid & 63;
    const int wv   = tid >> 6;
    const int l16  = lane & 15;
    const int quad = (lane >> 4) & 3;
    const int kc4  = lane >> 4;
    const int wr   = wv >> 1, wc = wv & 1;
    const int rowBase = blockIdx.y * 128;
    const int colBase = blockIdx.x * 128;

    __shared__ bf16_t sA[4096];
    __shared__ bf16_t sB[4096];

    const bf16_t* gA = A + (size_t)(rowBase + wv * 32 + l16) * K + kc4 * 8;
    const bf16_t* gB = Bw + (size_t)(colBase + wv * 32 + l16) * K + kc4 * 8;
    bf16_t* lA0 = &sA[(wv * 2) * 512];
    bf16_t* lA1 = &sA[(wv * 2 + 1) * 512];
    bf16_t* lB0 = &sB[(wv * 2) * 512];
    bf16_t* lB1 = &sB[(wv * 2 + 1) * 512];

    const f32x4 fz = {0.f, 0.f, 0.f, 0.f};
    f32x4 acc[4][4];
#pragma unroll
    for (int i = 0; i < 4; i++)
#pragma unroll
        for (int j = 0; j < 4; j++) acc[i][j] = fz;

    for (int k0 = 0; k0 < K; k0 += 32) {
        gl_lds16(gA, lA0);
        gl_lds16(gA + (size_t)16 * K, lA1);
        gl_lds16(gB, lB0);
        gl_lds16(gB + (size_t)16 * K, lB1);
        gA += 32; gB += 32;
        __syncthreads();

        bf16x8 aF[4], bF[4];
#pragma unroll
        for (int mi = 0; mi < 4; mi++)
            aF[mi] = *(const bf16x8*)(&sA[(wr * 4 + mi) * 512 + (quad * 16 + l16) * 8]);
#pragma unroll
        for (int ni = 0; ni < 4; ni++)
            bF[ni] = *(const bf16x8*)(&sB[(wc * 4 + ni) * 512 + (quad * 16 + l16) * 8]);
#pragma unroll
        for (int mi = 0; mi < 4; mi++)
#pragma unroll
            for (int ni = 0; ni < 4; ni++)
                acc[mi][ni] = __builtin_amdgcn_mfma_f32_16x16x32_bf16(
                    aF[mi], bF[ni], acc[mi][ni], 0, 0, 0);
        __syncthreads();
    }

#pragma unroll
    for (int mi = 0; mi < 4; mi++) {
#pragma unroll
        for (int ni = 0; ni < 4; ni++) {
            int row0 = rowBase + wr * 64 + mi * 16 + quad * 4;
            int col  = colBase + wc * 64 + ni * 16 + l16;
            float bvv = bias[col];
            if (z != 2) {
#pragma unroll
                for (int r = 0; r < 4; r++)
                    Cb[(size_t)(row0 + r) * N + col] = (bf16_t)(acc[mi][ni][r] + bvv);
            } else {
                int b  = row0 >> 11;
                int n0 = row0 & 2047;
                int hh = col >> 7;
                int dd = col & 127;
                bf16x4 p = {(bf16_t)(acc[mi][ni][0] + bvv), (bf16_t)(acc[mi][ni][1] + bvv),
                            (bf16_t)(acc[mi][ni][2] + bvv), (bf16_t)(acc[mi][ni][3] + bvv)};
                *(bf16x4*)(Cb + (size_t)((b * NH + hh) * DHEAD + dd) * NK + n0) = p;
            }
        }
    }
}

// ---------------------------------------------------------------------------
// Wo GEMM (MODE1): Cf = resid + relu(acc + bias)
// ---------------------------------------------------------------------------
__global__ __launch_bounds__(256) void gemm_wo(
    const bf16_t* __restrict__ A, const bf16_t* __restrict__ Bw,
    const float* __restrict__ bias, const float* resid, float* Cf, int M, int N, int K)
{
    const int tid  = threadIdx.x;
    const int lane = tid & 63;
    const int wv   = tid >> 6;
    const int l16  = lane & 15;
    const int quad = (lane >> 4) & 3;
    const int kc4  = lane >> 4;
    const int wr   = wv >> 1, wc = wv & 1;
    const int rowBase = blockIdx.y * 128;
    const int colBase = blockIdx.x * 128;

    __shared__ bf16_t sA[4096];
    __shared__ bf16_t sB[4096];

    const bf16_t* gA = A + (size_t)(rowBase + wv * 32 + l16) * K + kc4 * 8;
    const bf16_t* gB = Bw + (size_t)(colBase + wv * 32 + l16) * K + kc4 * 8;
    bf16_t* lA0 = &sA[(wv * 2) * 512];
    bf16_t* lA1 = &sA[(wv * 2 + 1) * 512];
    bf16_t* lB0 = &sB[(wv * 2) * 512];
    bf16_t* lB1 = &sB[(wv * 2 + 1) * 512];

    const f32x4 fz = {0.f, 0.f, 0.f, 0.f};
    f32x4 acc[4][4];
#pragma unroll
    for (int i = 0; i < 4; i++)
#pragma unroll
        for (int j = 0; j < 4; j++) acc[i][j] = fz;

    for (int k0 = 0; k0 < K; k0 += 32) {
        gl_lds16(gA, lA0);
        gl_lds16(gA + (size_t)16 * K, lA1);
        gl_lds16(gB, lB0);
        gl_lds16(gB + (size_t)16 * K, lB1);
        gA += 32; gB += 32;
        __syncthreads();

        bf16x8 aF[4], bF[4];
#pragma unroll
        for (int mi = 0; mi < 4; mi++)
            aF[mi] = *(const bf16x8*)(&sA[(wr * 4 + mi) * 512 + (quad * 16 + l16) * 8]);
#pragma unroll
        for (int ni = 0; ni < 4; ni++)
            bF[ni] = *(const bf16x8*)(&sB[(wc * 4 + ni) * 512 + (quad * 16 + l16) * 8]);
#pragma unroll
        for (int mi = 0; mi < 4; mi++)
#pragma unroll
            for (int ni = 0; ni < 4; ni++)
                acc[mi][ni] = __builtin_amdgcn_mfma_f32_16x16x32_bf16(
                    aF[mi], bF[ni], acc[mi][ni], 0, 0, 0);
        __syncthreads();
    }

#pragma unroll
    for (int mi = 0; mi < 4; mi++) {
#pragma unroll
        for (int ni = 0; ni < 4; ni++) {
            int row0 = rowBase + wr * 64 + mi * 16 + quad * 4;
            int col  = colBase + wc * 64 + ni * 16 + l16;
            float bvv = bias[col];
#pragma unroll
            for (int r = 0; r < 4; r++) {
                float v = acc[mi][ni][r] + bvv;
                v = v > 0.f ? v : 0.f;
                Cf[(size_t)(row0 + r) * N + col] =
                    resid[(size_t)(row0 + r) * N + col] + v;
            }
        }
    }
}

// ---------------------------------------------------------------------------
// Transposed flash attention: S^T = K Q^T, O^T = V^T P^T.
// v6 = R3 config (8 waves x 16 q-rows, K dbuf in LDS, defer-max) with the
// V LDS round-trip REMOVED: V^T fragments are read directly from global as
// bf16x8 (layout is exactly the A-operand fragment layout; V is L2-resident,
// 512 KB per (b,h), reused by 16 q-tile blocks).  Halves LDS read traffic
// (the measured bottleneck) and halves the staging/barrier-drain work.
// LDS: 32 KB (sK dbuf only).  Grid: x = bh, y = q-tile/128.
// ---------------------------------------------------------------------------
__global__ __launch_bounds__(512, 4) void attn_k(
    const bf16_t* __restrict__ qb, const bf16_t* __restrict__ kb,
    const bf16_t* __restrict__ vT, float* __restrict__ O)
{
    const int tid  = threadIdx.x;
    const int lane = tid & 63;
    const int wv   = tid >> 6;      // 0..7
    const int l16  = lane & 15;
    const int quad = (lane >> 4) & 3;
    const int bh   = blockIdx.x;    // bh-major: same bh -> same XCD
    const int b    = bh >> 3;
    const int h    = bh & 7;
    const int qt   = blockIdx.y * 128;
    const int qrow = b * NQ + qt + wv * 16;   // 16 q-rows per wave
    const int NKT  = NK / 64;       // 32 key-tiles

    __shared__ bf16_t sK[2][8192];  // dbuf: 16 K-frags of 1 KB (64 keys x 128 d)

    const bf16_t* gKb = kb + ((size_t)b * NK + l16) * DMODEL + h * DHEAD + quad * 8;
    const bf16_t* gVb = vT + ((size_t)bh * DHEAD + l16) * NK + quad * 8;

    // 16 K frags/tile, 8 waves: each wave stages 2 K frags.
    auto stage = [&](int tt, int bufi) {
        const int kt = tt * 64;
#pragma unroll
        for (int j = 0; j < 2; j++) {
            const int f = wv * 2 + j;
            const int kbi = f >> 2, c = f & 3;
            gl_lds16(gKb + (size_t)(kt + kbi * 16) * DMODEL + c * 32,
                     &sK[bufi][f * 512]);
        }
    };

    stage(0, 0);   // prologue prefetch overlaps the Q-fragment loads below

    // Q as B-operand fragments: q = qrow + l16, d = c*32 + quad*8
    bf16x8 qF[4];
#pragma unroll
    for (int c = 0; c < 4; c++)
        qF[c] = *(const bf16x8*)(qb + (size_t)(qrow + l16) * DMODEL +
                                 h * DHEAD + c * 32 + quad * 8);

    const f32x4 fz = {0.f, 0.f, 0.f, 0.f};
    f32x4 accO[8];                // O^T frags per d-block
#pragma unroll
    for (int db = 0; db < 8; db++) accO[db] = fz;
    float mq = -3e38f;
    float lq = 0.f;
    const float SC2 = 0.08838834764831845f * 1.44269504089f;  // log2(e)/sqrt(128)

    const int qa   = (quad & 1) * 2;
    const int srcA = l16 + 16 * qa;
    const int srcB = srcA + 16;
    const bool hi  = (quad >> 1) != 0;

    __syncthreads();              // tile 0 staged (vmcnt drained)
    int cur = 0;

    for (int t = 0; t < NKT; t++) {
        // ---- prefetch next K-tile into the alternate buffer (no wait here)
        if (t + 1 < NKT) stage(t + 1, cur ^ 1);

        // ---- S^T = K Q^T : A = K frags (LDS), B = Q frag
        f32x4 S[4];
        __builtin_amdgcn_s_setprio(1);
#pragma unroll
        for (int kb4 = 0; kb4 < 4; kb4++) {
            S[kb4] = fz;
#pragma unroll
            for (int c = 0; c < 4; c++) {
                bf16x8 kF = *(const bf16x8*)(&sK[cur][(kb4 * 4 + c) * 512 + lane * 8]);
                S[kb4] = __builtin_amdgcn_mfma_f32_16x16x32_bf16(kF, qF[c], S[kb4], 0, 0, 0);
            }
        }
        __builtin_amdgcn_s_setprio(0);

        // ---- online softmax (per lane q = l16; keys spread over quads)
        float mx = fmaxf(fmaxf(fmaxf(S[0][0], S[0][1]), fmaxf(S[0][2], S[0][3])),
                   fmaxf(fmaxf(S[1][0], S[1][1]), fmaxf(S[1][2], S[1][3])));
        mx = fmaxf(mx, fmaxf(fmaxf(fmaxf(S[2][0], S[2][1]), fmaxf(S[2][2], S[2][3])),
                       fmaxf(fmaxf(S[3][0], S[3][1]), fmaxf(S[3][2], S[3][3]))));
        mx = fmaxf(mx, __shfl_xor(mx, 16));
        mx = fmaxf(mx, __shfl_xor(mx, 32));
        // defer-max (T13): skip rescale while tile max stays within 2^8 of ref
        const bool need = !__all((mx - mq) * SC2 <= 8.f);
        float al = 1.f;
        if (need) {
            float mn = fmaxf(mq, mx);
            al = exp2f((mq - mn) * SC2);
            mq = mn;
        }
        const float mc = mq * SC2;
        float sum = 0.f;
#pragma unroll
        for (int kb4 = 0; kb4 < 4; kb4++)
#pragma unroll
            for (int r = 0; r < 4; r++) {
                float p = exp2f(fmaf(S[kb4][r], SC2, -mc));
                S[kb4][r] = p;
                sum += p;
            }
        lq = lq * al + sum;       // lane-local partial (this lane's 16 keys)
        if (need) {
#pragma unroll
            for (int db = 0; db < 8; db++)
#pragma unroll
                for (int r = 0; r < 4; r++) accO[db][r] *= al;
        }

        // ---- P: pack each C-frag into 2 dwords, shuffle into B-operand frags
        uint2 pk[4];
#pragma unroll
        for (int kb4 = 0; kb4 < 4; kb4++) {
            bf16x4 tt = {(bf16_t)S[kb4][0], (bf16_t)S[kb4][1],
                         (bf16_t)S[kb4][2], (bf16_t)S[kb4][3]};
            pk[kb4] = __builtin_bit_cast(uint2, tt);
        }
        bf16x8 pF[2];
#pragma unroll
        for (int kc = 0; kc < 2; kc++) {
            unsigned a0 = (unsigned)__shfl((int)pk[2 * kc].x, srcA);
            unsigned b0 = (unsigned)__shfl((int)pk[2 * kc + 1].x, srcA);
            unsigned a1 = (unsigned)__shfl((int)pk[2 * kc].y, srcA);
            unsigned b1 = (unsigned)__shfl((int)pk[2 * kc + 1].y, srcA);
            unsigned a2 = (unsigned)__shfl((int)pk[2 * kc].x, srcB);
            unsigned b2 = (unsigned)__shfl((int)pk[2 * kc + 1].x, srcB);
            unsigned a3 = (unsigned)__shfl((int)pk[2 * kc].y, srcB);
            unsigned b3 = (unsigned)__shfl((int)pk[2 * kc + 1].y, srcB);
            uint4 w = {hi ? b0 : a0, hi ? b1 : a1, hi ? b2 : a2, hi ? b3 : a3};
            pF[kc] = __builtin_bit_cast(bf16x8, w);
        }

        // ---- O^T += V^T P^T : A = V^T frags DIRECT FROM GLOBAL (L2-resident)
        const int kt = t * 64;
        __builtin_amdgcn_s_setprio(1);
#pragma unroll
        for (int kc = 0; kc < 2; kc++)
#pragma unroll
            for (int db = 0; db < 8; db++) {
                bf16x8 vF = *(const bf16x8*)(gVb + (size_t)(db * 16) * NK + kt + kc * 32);
                accO[db] = __builtin_amdgcn_mfma_f32_16x16x32_bf16(vF, pF[kc], accO[db], 0, 0, 0);
            }
        __builtin_amdgcn_s_setprio(0);

        // single barrier per iter: drains the K prefetch + releases buffers
        __syncthreads();
        cur ^= 1;
    }

    // finalize denominator (cross-quad partials)
    float s = lq;
    s += __shfl_xor(s, 16);
    s += __shfl_xor(s, 32);
    const float inv = 1.0f / s;

    // O = acc/l + q residual;  O^T frag: q = l16, d = db*16 + quad*4 + r
    const int grow = qrow + l16;
#pragma unroll
    for (int db = 0; db < 8; db++) {
        const int gcol = h * DHEAD + db * 16 + quad * 4;
        bf16x4 qr = *(const bf16x4*)(qb + (size_t)grow * DMODEL + gcol);
        f32x4 o;
#pragma unroll
        for (int r = 0; r < 4; r++)
            o[r] = accO[db][r] * inv + (float)qr[r];
        *(f32x4*)(O + (size_t)grow * DMODEL + gcol) = o;
    }
}

// ---------------------------------------------------------------------------
// LayerNorm over rows of 1024; optional extra bf16 output
// ---------------------------------------------------------------------------
__global__ __launch_bounds__(256) void ln_k(
    const float* __restrict__ X, const float* __restrict__ g,
    const float* __restrict__ bta, float* __restrict__ Yf, bf16_t* Yb)
{
    const int row = blockIdx.x;
    const int t = threadIdx.x;
    float4 x = *(const float4*)(X + (size_t)row * DMODEL + t * 4);
    float s  = x.x + x.y + x.z + x.w;
    float sq = x.x * x.x + x.y * x.y + x.z * x.z + x.w * x.w;
#pragma unroll
    for (int o = 1; o < 64; o <<= 1) {
        s  += __shfl_xor(s, o);
        sq += __shfl_xor(sq, o);
    }
    __shared__ float ls[8];
    int w = t >> 6, ln = t & 63;
    if (ln == 0) { ls[w] = s; ls[4 + w] = sq; }
    __syncthreads();
    s  = ls[0] + ls[1] + ls[2] + ls[3];
    sq = ls[4] + ls[5] + ls[6] + ls[7];
    float mu  = s * (1.f / DMODEL);
    float var = sq * (1.f / DMODEL) - mu * mu;
    float rs  = rsqrtf(var + 1e-5f);
    float4 gv = *(const float4*)(g + t * 4);
    float4 bv = *(const float4*)(bta + t * 4);
    float4 y;
    y.x = (x.x - mu) * rs * gv.x + bv.x;
    y.y = (x.y - mu) * rs * gv.y + bv.y;
    y.z = (x.z - mu) * rs * gv.z + bv.z;
    y.w = (x.w - mu) * rs * gv.w + bv.w;
    *(float4*)(Yf + (size_t)row * DMODEL + t * 4) = y;
    if (Yb) {
        bf16x4 yb = {(bf16_t)y.x, (bf16_t)y.y, (bf16_t)y.z, (bf16_t)y.w};
        *(bf16x4*)(Yb + (size_t)row * DMODEL + t * 4) = yb;
    }
}

// ---------------------------------------------------------------------------
extern "C" void kernel_launch(void* const* d_in, const int* in_sizes, int n_in,
                              void* d_out, int out_size, void* d_ws, size_t ws_size,
                              hipStream_t stream)
{
    const float* Q  = (const float*)d_in[0];
    const float* Kx = (const float*)d_in[1];
    const float* Wq = (const float*)d_in[2];
    const float* bq = (const float*)d_in[3];
    const float* Wk = (const float*)d_in[4];
    const float* bk = (const float*)d_in[5];
    const float* Wv = (const float*)d_in[6];
    const float* bv = (const float*)d_in[7];
    const float* Wo = (const float*)d_in[8];
    const float* bo = (const float*)d_in[9];
    const float* g0 = (const float*)d_in[10];
    const float* b0 = (const float*)d_in[11];
    const float* g1 = (const float*)d_in[12];
    const float* b1 = (const float*)d_in[13];
    float* out = (float*)d_out;

    char* ws = (char*)d_ws;
    bf16_t* Qc  = (bf16_t*)(ws);                  // 16,777,216
    bf16_t* Kc  = (bf16_t*)(ws + 16777216);       // 16,777,216
    bf16_t* Wqc = (bf16_t*)(ws + 33554432);       // 2,097,152
    bf16_t* Wkc = (bf16_t*)(ws + 35651584);
    bf16_t* Wvc = (bf16_t*)(ws + 37748736);
    bf16_t* Woc = (bf16_t*)(ws + 39845888);
    bf16_t* qbb = (bf16_t*)(ws + 41943040);       // 16,777,216
    bf16_t* kbb = (bf16_t*)(ws + 58720256);       // 16,777,216
    bf16_t* vT  = (bf16_t*)(ws + 75497472);       // 16,777,216
    float*  Obuf = (float*)(ws + 92274688);       // 33,554,432
    float*  Lf  = (float*)(ws);                   // alias Qc+Kc (dead after proj)
    bf16_t* Lb  = kbb;                            // alias kbb (dead after attn)

    CvtArgs ca;
    ca.s[0] = Q;  ca.d[0] = Qc;  ca.n[0] = B_DIM * NQ * DMODEL;
    ca.s[1] = Kx; ca.d[1] = Kc;  ca.n[1] = B_DIM * NK * DMODEL;
    ca.s[2] = Wq; ca.d[2] = Wqc; ca.n[2] = DMODEL * DMODEL;
    ca.s[3] = Wk; ca.d[3] = Wkc; ca.n[3] = DMODEL * DMODEL;
    ca.s[4] = Wv; ca.d[4] = Wvc; ca.n[4] = DMODEL * DMODEL;
    ca.s[5] = Wo; ca.d[5] = Woc; ca.n[5] = DMODEL * DMODEL;
    cvt_k<<<dim3(512, 6), 256, 0, stream>>>(ca);

    const int M = B_DIM * NQ;  // 8192

    proj_k<<<dim3(DMODEL / 128, M / 128, 3), 256, 0, stream>>>(
        Qc, Kc, Wqc, Wkc, Wvc, bq, bk, bv, qbb, kbb, vT);

    attn_k<<<dim3(B_DIM * NH, NQ / 128), 512, 0, stream>>>(qbb, kbb, vT, Obuf);

    ln_k<<<dim3(M), 256, 0, stream>>>(Obuf, g0, b0, Lf, Lb);

    gemm_wo<<<dim3(DMODEL / 128, M / 128), 256, 0, stream>>>(
        Lb, Woc, bo, Lf, Lf, M, DMODEL, DMODEL);

    ln_k<<<dim3(M), 256, 0, stream>>>(Lf, g1, b1, out, nullptr);
}

// Round 8
// 416.327 us; speedup vs baseline: 1.4312x; 1.4312x over previous
//
#include <hip/hip_runtime.h>
#include <hip/hip_bf16.h>

typedef __bf16 bf16_t;
typedef __bf16 bf16x8 __attribute__((ext_vector_type(8)));
typedef __bf16 bf16x4 __attribute__((ext_vector_type(4)));
typedef float f32x4 __attribute__((ext_vector_type(4)));

#define B_DIM 4
#define NQ 2048
#define NK 2048
#define DMODEL 1024
#define NH 8
#define DHEAD 128

#define AS1 __attribute__((address_space(1)))
#define AS3 __attribute__((address_space(3)))

__device__ __forceinline__ void gl_lds16(const void* g, void* l) {
    __builtin_amdgcn_global_load_lds((const AS1 void*)g, (AS3 void*)l, 16, 0, 0);
}

// ---------------------------------------------------------------------------
// fp32 -> bf16 conversion, 6 pairs selected by blockIdx.y
// ---------------------------------------------------------------------------
struct CvtArgs {
    const float* s[6];
    bf16_t* d[6];
    int n[6];
};

__global__ __launch_bounds__(256) void cvt_k(CvtArgs a) {
    const int p = blockIdx.y;
    const float* s = a.s[p];
    bf16_t* d = a.d[p];
    const int n = a.n[p];
    const int stride = gridDim.x * 256 * 8;
    for (int i = (blockIdx.x * 256 + threadIdx.x) * 8; i < n; i += stride) {
        float4 x0 = *(const float4*)(s + i);
        float4 x1 = *(const float4*)(s + i + 4);
        bf16x8 o = {(bf16_t)x0.x, (bf16_t)x0.y, (bf16_t)x0.z, (bf16_t)x0.w,
                    (bf16_t)x1.x, (bf16_t)x1.y, (bf16_t)x1.z, (bf16_t)x1.w};
        *(bf16x8*)(d + i) = o;
    }
}

// ---------------------------------------------------------------------------
// Fused Q/K/V projection: z = blockIdx.z selects (A, W, bias, epilogue).
// C[M,N] = A[M,1024] * W[N,1024]^T + bias.  z==2 scatters to vT.
// ---------------------------------------------------------------------------
__global__ __launch_bounds__(256) void proj_k(
    const bf16_t* Qc, const bf16_t* Kc,
    const bf16_t* Wqc, const bf16_t* Wkc, const bf16_t* Wvc,
    const float* bq, const float* bk, const float* bv,
    bf16_t* qbb, bf16_t* kbb, bf16_t* vT)
{
    const int K = DMODEL, N = DMODEL;
    const int z = blockIdx.z;
    const bf16_t* A  = (z == 0) ? Qc : Kc;
    const bf16_t* Bw = (z == 0) ? Wqc : (z == 1) ? Wkc : Wvc;
    const float* bias = (z == 0) ? bq : (z == 1) ? bk : bv;
    bf16_t* Cb = (z == 0) ? qbb : (z == 1) ? kbb : vT;

    const int tid  = threadIdx.x;
    const int lane = tid & 63;
    const int wv   = tid >> 6;
    const int l16  = lane & 15;
    const int quad = (lane >> 4) & 3;
    const int kc4  = lane >> 4;
    const int wr   = wv >> 1, wc = wv & 1;
    const int rowBase = blockIdx.y * 128;
    const int colBase = blockIdx.x * 128;

    __shared__ bf16_t sA[4096];
    __shared__ bf16_t sB[4096];

    const bf16_t* gA = A + (size_t)(rowBase + wv * 32 + l16) * K + kc4 * 8;
    const bf16_t* gB = Bw + (size_t)(colBase + wv * 32 + l16) * K + kc4 * 8;
    bf16_t* lA0 = &sA[(wv * 2) * 512];
    bf16_t* lA1 = &sA[(wv * 2 + 1) * 512];
    bf16_t* lB0 = &sB[(wv * 2) * 512];
    bf16_t* lB1 = &sB[(wv * 2 + 1) * 512];

    const f32x4 fz = {0.f, 0.f, 0.f, 0.f};
    f32x4 acc[4][4];
#pragma unroll
    for (int i = 0; i < 4; i++)
#pragma unroll
        for (int j = 0; j < 4; j++) acc[i][j] = fz;

    for (int k0 = 0; k0 < K; k0 += 32) {
        gl_lds16(gA, lA0);
        gl_lds16(gA + (size_t)16 * K, lA1);
        gl_lds16(gB, lB0);
        gl_lds16(gB + (size_t)16 * K, lB1);
        gA += 32; gB += 32;
        __syncthreads();

        bf16x8 aF[4], bF[4];
#pragma unroll
        for (int mi = 0; mi < 4; mi++)
            aF[mi] = *(const bf16x8*)(&sA[(wr * 4 + mi) * 512 + (quad * 16 + l16) * 8]);
#pragma unroll
        for (int ni = 0; ni < 4; ni++)
            bF[ni] = *(const bf16x8*)(&sB[(wc * 4 + ni) * 512 + (quad * 16 + l16) * 8]);
#pragma unroll
        for (int mi = 0; mi < 4; mi++)
#pragma unroll
            for (int ni = 0; ni < 4; ni++)
                acc[mi][ni] = __builtin_amdgcn_mfma_f32_16x16x32_bf16(
                    aF[mi], bF[ni], acc[mi][ni], 0, 0, 0);
        __syncthreads();
    }

#pragma unroll
    for (int mi = 0; mi < 4; mi++) {
#pragma unroll
        for (int ni = 0; ni < 4; ni++) {
            int row0 = rowBase + wr * 64 + mi * 16 + quad * 4;
            int col  = colBase + wc * 64 + ni * 16 + l16;
            float bvv = bias[col];
            if (z != 2) {
#pragma unroll
                for (int r = 0; r < 4; r++)
                    Cb[(size_t)(row0 + r) * N + col] = (bf16_t)(acc[mi][ni][r] + bvv);
            } else {
                int b  = row0 >> 11;
                int n0 = row0 & 2047;
                int hh = col >> 7;
                int dd = col & 127;
                bf16x4 p = {(bf16_t)(acc[mi][ni][0] + bvv), (bf16_t)(acc[mi][ni][1] + bvv),
                            (bf16_t)(acc[mi][ni][2] + bvv), (bf16_t)(acc[mi][ni][3] + bvv)};
                *(bf16x4*)(Cb + (size_t)((b * NH + hh) * DHEAD + dd) * NK + n0) = p;
            }
        }
    }
}

// ---------------------------------------------------------------------------
// Wo GEMM (MODE1): Cf = resid + relu(acc + bias).  resid is the bf16 LN
// output (Lb) -- saves ln1's f32 store and 32->16 MB of resid read traffic.
// bf16 rounding of resid (<=0.004 on O(1) values) is well inside threshold.
// ---------------------------------------------------------------------------
__global__ __launch_bounds__(256) void gemm_wo(
    const bf16_t* __restrict__ A, const bf16_t* __restrict__ Bw,
    const float* __restrict__ bias, const bf16_t* resid, float* Cf,
    int M, int N, int K)
{
    const int tid  = threadIdx.x;
    const int lane = tid & 63;
    const int wv   = tid >> 6;
    const int l16  = lane & 15;
    const int quad = (lane >> 4) & 3;
    const int kc4  = lane >> 4;
    const int wr   = wv >> 1, wc = wv & 1;
    const int rowBase = blockIdx.y * 128;
    const int colBase = blockIdx.x * 128;

    __shared__ bf16_t sA[4096];
    __shared__ bf16_t sB[4096];

    const bf16_t* gA = A + (size_t)(rowBase + wv * 32 + l16) * K + kc4 * 8;
    const bf16_t* gB = Bw + (size_t)(colBase + wv * 32 + l16) * K + kc4 * 8;
    bf16_t* lA0 = &sA[(wv * 2) * 512];
    bf16_t* lA1 = &sA[(wv * 2 + 1) * 512];
    bf16_t* lB0 = &sB[(wv * 2) * 512];
    bf16_t* lB1 = &sB[(wv * 2 + 1) * 512];

    const f32x4 fz = {0.f, 0.f, 0.f, 0.f};
    f32x4 acc[4][4];
#pragma unroll
    for (int i = 0; i < 4; i++)
#pragma unroll
        for (int j = 0; j < 4; j++) acc[i][j] = fz;

    for (int k0 = 0; k0 < K; k0 += 32) {
        gl_lds16(gA, lA0);
        gl_lds16(gA + (size_t)16 * K, lA1);
        gl_lds16(gB, lB0);
        gl_lds16(gB + (size_t)16 * K, lB1);
        gA += 32; gB += 32;
        __syncthreads();

        bf16x8 aF[4], bF[4];
#pragma unroll
        for (int mi = 0; mi < 4; mi++)
            aF[mi] = *(const bf16x8*)(&sA[(wr * 4 + mi) * 512 + (quad * 16 + l16) * 8]);
#pragma unroll
        for (int ni = 0; ni < 4; ni++)
            bF[ni] = *(const bf16x8*)(&sB[(wc * 4 + ni) * 512 + (quad * 16 + l16) * 8]);
#pragma unroll
        for (int mi = 0; mi < 4; mi++)
#pragma unroll
            for (int ni = 0; ni < 4; ni++)
                acc[mi][ni] = __builtin_amdgcn_mfma_f32_16x16x32_bf16(
                    aF[mi], bF[ni], acc[mi][ni], 0, 0, 0);
        __syncthreads();
    }

#pragma unroll
    for (int mi = 0; mi < 4; mi++) {
#pragma unroll
        for (int ni = 0; ni < 4; ni++) {
            int row0 = rowBase + wr * 64 + mi * 16 + quad * 4;
            int col  = colBase + wc * 64 + ni * 16 + l16;
            float bvv = bias[col];
#pragma unroll
            for (int r = 0; r < 4; r++) {
                float v = acc[mi][ni][r] + bvv;
                v = v > 0.f ? v : 0.f;
                Cf[(size_t)(row0 + r) * N + col] =
                    (float)resid[(size_t)(row0 + r) * N + col] + v;
            }
        }
    }
}

// ---------------------------------------------------------------------------
// Transposed flash attention: S^T = K Q^T, O^T = V^T P^T.
// v8 = R3/v4 config restored (best measured: attn ~130 us).
// 8 waves x 16 q-rows (512 threads), q-tile 128, KVBLK=64 double-buffered
// LDS (64 KB) -> 2 blocks/CU = 4 waves/SIMD.  Defer-max (T13).
// [R6: key-split regressed via HBM partial-traffic amplification.
//  R7: V-direct-from-global regressed 2.2x -- L1/VMEM path is far slower
//  than async-staged LDS for the PV operand.  Keep V in LDS.]
// Grid: x = bh (XCD-local), y = q-tile/128.
// ---------------------------------------------------------------------------
__global__ __launch_bounds__(512, 4) void attn_k(
    const bf16_t* __restrict__ qb, const bf16_t* __restrict__ kb,
    const bf16_t* __restrict__ vT, float* __restrict__ O)
{
    const int tid  = threadIdx.x;
    const int lane = tid & 63;
    const int wv   = tid >> 6;      // 0..7
    const int l16  = lane & 15;
    const int quad = (lane >> 4) & 3;
    const int bh   = blockIdx.x;    // bh-major: same bh -> same XCD
    const int b    = bh >> 3;
    const int h    = bh & 7;
    const int qt   = blockIdx.y * 128;
    const int qrow = b * NQ + qt + wv * 16;   // 16 q-rows per wave
    const int NKT  = NK / 64;       // 32 key-tiles

    __shared__ bf16_t sK[2][8192];  // dbuf: 16 K-frags of 1 KB (64 keys x 128 d)
    __shared__ bf16_t sV[2][8192];  // dbuf: 16 V^T-frags of 1 KB (128 d x 64 k)

    const bf16_t* gKb = kb + ((size_t)b * NK + l16) * DMODEL + h * DHEAD + quad * 8;
    const bf16_t* gVb = vT + ((size_t)bh * DHEAD + l16) * NK + quad * 8;

    // 32 frags/tile-pair, 8 waves: each wave stages 2 K frags + 2 V frags.
    auto stage = [&](int tt, int bufi) {
        const int kt = tt * 64;
#pragma unroll
        for (int j = 0; j < 2; j++) {
            const int f = wv * 2 + j;
            const int kbi = f >> 2, c = f & 3;
            gl_lds16(gKb + (size_t)(kt + kbi * 16) * DMODEL + c * 32,
                     &sK[bufi][f * 512]);
        }
#pragma unroll
        for (int j = 0; j < 2; j++) {
            const int g = wv * 2 + j;
            const int dbi = g >> 1, kc = g & 1;
            gl_lds16(gVb + (size_t)(dbi * 16) * NK + kt + kc * 32,
                     &sV[bufi][g * 512]);
        }
    };

    stage(0, 0);   // prologue prefetch overlaps the Q-fragment loads below

    // Q as B-operand fragments: q = qrow + l16, d = c*32 + quad*8
    bf16x8 qF[4];
#pragma unroll
    for (int c = 0; c < 4; c++)
        qF[c] = *(const bf16x8*)(qb + (size_t)(qrow + l16) * DMODEL +
                                 h * DHEAD + c * 32 + quad * 8);

    const f32x4 fz = {0.f, 0.f, 0.f, 0.f};
    f32x4 accO[8];                // O^T frags per d-block
#pragma unroll
    for (int db = 0; db < 8; db++) accO[db] = fz;
    float mq = -3e38f;
    float lq = 0.f;
    const float SC2 = 0.08838834764831845f * 1.44269504089f;  // log2(e)/sqrt(128)

    const int qa   = (quad & 1) * 2;
    const int srcA = l16 + 16 * qa;
    const int srcB = srcA + 16;
    const bool hi  = (quad >> 1) != 0;

    __syncthreads();              // tile 0 staged (vmcnt drained)
    int cur = 0;

    for (int t = 0; t < NKT; t++) {
        // ---- prefetch next tile into the alternate buffer (no wait here)
        if (t + 1 < NKT) stage(t + 1, cur ^ 1);

        // ---- S^T = K Q^T : A = K frags, B = Q frag
        f32x4 S[4];
        __builtin_amdgcn_s_setprio(1);
#pragma unroll
        for (int kb4 = 0; kb4 < 4; kb4++) {
            S[kb4] = fz;
#pragma unroll
            for (int c = 0; c < 4; c++) {
                bf16x8 kF = *(const bf16x8*)(&sK[cur][(kb4 * 4 + c) * 512 + lane * 8]);
                S[kb4] = __builtin_amdgcn_mfma_f32_16x16x32_bf16(kF, qF[c], S[kb4], 0, 0, 0);
            }
        }
        __builtin_amdgcn_s_setprio(0);

        // ---- online softmax (per lane q = l16; keys spread over quads)
        float mx = fmaxf(fmaxf(fmaxf(S[0][0], S[0][1]), fmaxf(S[0][2], S[0][3])),
                   fmaxf(fmaxf(S[1][0], S[1][1]), fmaxf(S[1][2], S[1][3])));
        mx = fmaxf(mx, fmaxf(fmaxf(fmaxf(S[2][0], S[2][1]), fmaxf(S[2][2], S[2][3])),
                       fmaxf(fmaxf(S[3][0], S[3][1]), fmaxf(S[3][2], S[3][3]))));
        mx = fmaxf(mx, __shfl_xor(mx, 16));
        mx = fmaxf(mx, __shfl_xor(mx, 32));
        // defer-max (T13): skip rescale while tile max stays within 2^8 of ref
        const bool need = !__all((mx - mq) * SC2 <= 8.f);
        float al = 1.f;
        if (need) {
            float mn = fmaxf(mq, mx);
            al = exp2f((mq - mn) * SC2);
            mq = mn;
        }
        const float mc = mq * SC2;
        float sum = 0.f;
#pragma unroll
        for (int kb4 = 0; kb4 < 4; kb4++)
#pragma unroll
            for (int r = 0; r < 4; r++) {
                float p = exp2f(fmaf(S[kb4][r], SC2, -mc));
                S[kb4][r] = p;
                sum += p;
            }
        lq = lq * al + sum;       // lane-local partial (this lane's 16 keys)
        if (need) {
#pragma unroll
            for (int db = 0; db < 8; db++)
#pragma unroll
                for (int r = 0; r < 4; r++) accO[db][r] *= al;
        }

        // ---- P: pack each C-frag into 2 dwords, shuffle into B-operand frags
        uint2 pk[4];
#pragma unroll
        for (int kb4 = 0; kb4 < 4; kb4++) {
            bf16x4 tt = {(bf16_t)S[kb4][0], (bf16_t)S[kb4][1],
                         (bf16_t)S[kb4][2], (bf16_t)S[kb4][3]};
            pk[kb4] = __builtin_bit_cast(uint2, tt);
        }
        bf16x8 pF[2];
#pragma unroll
        for (int kc = 0; kc < 2; kc++) {
            unsigned a0 = (unsigned)__shfl((int)pk[2 * kc].x, srcA);
            unsigned b0 = (unsigned)__shfl((int)pk[2 * kc + 1].x, srcA);
            unsigned a1 = (unsigned)__shfl((int)pk[2 * kc].y, srcA);
            unsigned b1 = (unsigned)__shfl((int)pk[2 * kc + 1].y, srcA);
            unsigned a2 = (unsigned)__shfl((int)pk[2 * kc].x, srcB);
            unsigned b2 = (unsigned)__shfl((int)pk[2 * kc + 1].x, srcB);
            unsigned a3 = (unsigned)__shfl((int)pk[2 * kc].y, srcB);
            unsigned b3 = (unsigned)__shfl((int)pk[2 * kc + 1].y, srcB);
            uint4 w = {hi ? b0 : a0, hi ? b1 : a1, hi ? b2 : a2, hi ? b3 : a3};
            pF[kc] = __builtin_bit_cast(bf16x8, w);
        }

        // ---- O^T += V^T P^T : A = V^T frags, B = P frag
        __builtin_amdgcn_s_setprio(1);
#pragma unroll
        for (int kc = 0; kc < 2; kc++)
#pragma unroll
            for (int db = 0; db < 8; db++) {
                bf16x8 vF = *(const bf16x8*)(&sV[cur][(db * 2 + kc) * 512 + lane * 8]);
                accO[db] = __builtin_amdgcn_mfma_f32_16x16x32_bf16(vF, pF[kc], accO[db], 0, 0, 0);
            }
        __builtin_amdgcn_s_setprio(0);

        // single barrier per iter: drains the prefetch + releases buffers
        __syncthreads();
        cur ^= 1;
    }

    // finalize denominator (cross-quad partials)
    float s = lq;
    s += __shfl_xor(s, 16);
    s += __shfl_xor(s, 32);
    const float inv = 1.0f / s;

    // O = acc/l + q residual;  O^T frag: q = l16, d = db*16 + quad*4 + r
    const int grow = qrow + l16;
#pragma unroll
    for (int db = 0; db < 8; db++) {
        const int gcol = h * DHEAD + db * 16 + quad * 4;
        bf16x4 qr = *(const bf16x4*)(qb + (size_t)grow * DMODEL + gcol);
        f32x4 o;
#pragma unroll
        for (int r = 0; r < 4; r++)
            o[r] = accO[db][r] * inv + (float)qr[r];
        *(f32x4*)(O + (size_t)grow * DMODEL + gcol) = o;
    }
}

// ---------------------------------------------------------------------------
// LayerNorm over rows of 1024; both outputs optional (nullptr to skip)
// ---------------------------------------------------------------------------
__global__ __launch_bounds__(256) void ln_k(
    const float* __restrict__ X, const float* __restrict__ g,
    const float* __restrict__ bta, float* __restrict__ Yf, bf16_t* Yb)
{
    const int row = blockIdx.x;
    const int t = threadIdx.x;
    float4 x = *(const float4*)(X + (size_t)row * DMODEL + t * 4);
    float s  = x.x + x.y + x.z + x.w;
    float sq = x.x * x.x + x.y * x.y + x.z * x.z + x.w * x.w;
#pragma unroll
    for (int o = 1; o < 64; o <<= 1) {
        s  += __shfl_xor(s, o);
        sq += __shfl_xor(sq, o);
    }
    __shared__ float ls[8];
    int w = t >> 6, ln = t & 63;
    if (ln == 0) { ls[w] = s; ls[4 + w] = sq; }
    __syncthreads();
    s  = ls[0] + ls[1] + ls[2] + ls[3];
    sq = ls[4] + ls[5] + ls[6] + ls[7];
    float mu  = s * (1.f / DMODEL);
    float var = sq * (1.f / DMODEL) - mu * mu;
    float rs  = rsqrtf(var + 1e-5f);
    float4 gv = *(const float4*)(g + t * 4);
    float4 bv = *(const float4*)(bta + t * 4);
    float4 y;
    y.x = (x.x - mu) * rs * gv.x + bv.x;
    y.y = (x.y - mu) * rs * gv.y + bv.y;
    y.z = (x.z - mu) * rs * gv.z + bv.z;
    y.w = (x.w - mu) * rs * gv.w + bv.w;
    if (Yf)
        *(float4*)(Yf + (size_t)row * DMODEL + t * 4) = y;
    if (Yb) {
        bf16x4 yb = {(bf16_t)y.x, (bf16_t)y.y, (bf16_t)y.z, (bf16_t)y.w};
        *(bf16x4*)(Yb + (size_t)row * DMODEL + t * 4) = yb;
    }
}

// ---------------------------------------------------------------------------
extern "C" void kernel_launch(void* const* d_in, const int* in_sizes, int n_in,
                              void* d_out, int out_size, void* d_ws, size_t ws_size,
                              hipStream_t stream)
{
    const float* Q  = (const float*)d_in[0];
    const float* Kx = (const float*)d_in[1];
    const float* Wq = (const float*)d_in[2];
    const float* bq = (const float*)d_in[3];
    const float* Wk = (const float*)d_in[4];
    const float* bk = (const float*)d_in[5];
    const float* Wv = (const float*)d_in[6];
    const float* bv = (const float*)d_in[7];
    const float* Wo = (const float*)d_in[8];
    const float* bo = (const float*)d_in[9];
    const float* g0 = (const float*)d_in[10];
    const float* b0 = (const float*)d_in[11];
    const float* g1 = (const float*)d_in[12];
    const float* b1 = (const float*)d_in[13];
    float* out = (float*)d_out;

    char* ws = (char*)d_ws;
    bf16_t* Qc  = (bf16_t*)(ws);                  // 16,777,216
    bf16_t* Kc  = (bf16_t*)(ws + 16777216);       // 16,777,216
    bf16_t* Wqc = (bf16_t*)(ws + 33554432);       // 2,097,152
    bf16_t* Wkc = (bf16_t*)(ws + 35651584);
    bf16_t* Wvc = (bf16_t*)(ws + 37748736);
    bf16_t* Woc = (bf16_t*)(ws + 39845888);
    bf16_t* qbb = (bf16_t*)(ws + 41943040);       // 16,777,216
    bf16_t* kbb = (bf16_t*)(ws + 58720256);       // 16,777,216
    bf16_t* vT  = (bf16_t*)(ws + 75497472);       // 16,777,216
    float*  Obuf = (float*)(ws + 92274688);       // 33,554,432
    float*  Lf  = (float*)(ws);                   // alias Qc+Kc (dead after proj)
    bf16_t* Lb  = kbb;                            // alias kbb (dead after attn)

    CvtArgs ca;
    ca.s[0] = Q;  ca.d[0] = Qc;  ca.n[0] = B_DIM * NQ * DMODEL;
    ca.s[1] = Kx; ca.d[1] = Kc;  ca.n[1] = B_DIM * NK * DMODEL;
    ca.s[2] = Wq; ca.d[2] = Wqc; ca.n[2] = DMODEL * DMODEL;
    ca.s[3] = Wk; ca.d[3] = Wkc; ca.n[3] = DMODEL * DMODEL;
    ca.s[4] = Wv; ca.d[4] = Wvc; ca.n[4] = DMODEL * DMODEL;
    ca.s[5] = Wo; ca.d[5] = Woc; ca.n[5] = DMODEL * DMODEL;
    cvt_k<<<dim3(512, 6), 256, 0, stream>>>(ca);

    const int M = B_DIM * NQ;  // 8192

    proj_k<<<dim3(DMODEL / 128, M / 128, 3), 256, 0, stream>>>(
        Qc, Kc, Wqc, Wkc, Wvc, bq, bk, bv, qbb, kbb, vT);

    attn_k<<<dim3(B_DIM * NH, NQ / 128), 512, 0, stream>>>(qbb, kbb, vT, Obuf);

    // ln1: bf16 output only (gemm_wo reads resid as bf16)
    ln_k<<<dim3(M), 256, 0, stream>>>(Obuf, g0, b0, nullptr, Lb);

    gemm_wo<<<dim3(DMODEL / 128, M / 128), 256, 0, stream>>>(
        Lb, Woc, bo, Lb, Lf, M, DMODEL, DMODEL);

    ln_k<<<dim3(M), 256, 0, stream>>>(Lf, g1, b1, out, nullptr);
}

// Round 9
// 407.163 us; speedup vs baseline: 1.4634x; 1.0225x over previous
//
#include <hip/hip_runtime.h>
#include <hip/hip_bf16.h>

typedef __bf16 bf16_t;
typedef __bf16 bf16x8 __attribute__((ext_vector_type(8)));
typedef __bf16 bf16x4 __attribute__((ext_vector_type(4)));
typedef float f32x4 __attribute__((ext_vector_type(4)));

#define B_DIM 4
#define NQ 2048
#define NK 2048
#define DMODEL 1024
#define NH 8
#define DHEAD 128

#define AS1 __attribute__((address_space(1)))
#define AS3 __attribute__((address_space(3)))

__device__ __forceinline__ void gl_lds16(const void* g, void* l) {
    __builtin_amdgcn_global_load_lds((const AS1 void*)g, (AS3 void*)l, 16, 0, 0);
}

// ---------------------------------------------------------------------------
// fp32 -> bf16 conversion, 6 pairs selected by blockIdx.y
// ---------------------------------------------------------------------------
struct CvtArgs {
    const float* s[6];
    bf16_t* d[6];
    int n[6];
};

__global__ __launch_bounds__(256) void cvt_k(CvtArgs a) {
    const int p = blockIdx.y;
    const float* s = a.s[p];
    bf16_t* d = a.d[p];
    const int n = a.n[p];
    const int stride = gridDim.x * 256 * 8;
    for (int i = (blockIdx.x * 256 + threadIdx.x) * 8; i < n; i += stride) {
        float4 x0 = *(const float4*)(s + i);
        float4 x1 = *(const float4*)(s + i + 4);
        bf16x8 o = {(bf16_t)x0.x, (bf16_t)x0.y, (bf16_t)x0.z, (bf16_t)x0.w,
                    (bf16_t)x1.x, (bf16_t)x1.y, (bf16_t)x1.z, (bf16_t)x1.w};
        *(bf16x8*)(d + i) = o;
    }
}

// ---------------------------------------------------------------------------
// Fused Q/K/V projection: z = blockIdx.z selects (A, W, bias, epilogue).
// C[M,N] = A[M,1024] * W[N,1024]^T + bias.  z==2 scatters to vT.
// ---------------------------------------------------------------------------
__global__ __launch_bounds__(256) void proj_k(
    const bf16_t* Qc, const bf16_t* Kc,
    const bf16_t* Wqc, const bf16_t* Wkc, const bf16_t* Wvc,
    const float* bq, const float* bk, const float* bv,
    bf16_t* qbb, bf16_t* kbb, bf16_t* vT)
{
    const int K = DMODEL, N = DMODEL;
    const int z = blockIdx.z;
    const bf16_t* A  = (z == 0) ? Qc : Kc;
    const bf16_t* Bw = (z == 0) ? Wqc : (z == 1) ? Wkc : Wvc;
    const float* bias = (z == 0) ? bq : (z == 1) ? bk : bv;
    bf16_t* Cb = (z == 0) ? qbb : (z == 1) ? kbb : vT;

    const int tid  = threadIdx.x;
    const int lane = tid & 63;
    const int wv   = tid >> 6;
    const int l16  = lane & 15;
    const int quad = (lane >> 4) & 3;
    const int kc4  = lane >> 4;
    const int wr   = wv >> 1, wc = wv & 1;
    const int rowBase = blockIdx.y * 128;
    const int colBase = blockIdx.x * 128;

    __shared__ bf16_t sA[4096];
    __shared__ bf16_t sB[4096];

    const bf16_t* gA = A + (size_t)(rowBase + wv * 32 + l16) * K + kc4 * 8;
    const bf16_t* gB = Bw + (size_t)(colBase + wv * 32 + l16) * K + kc4 * 8;
    bf16_t* lA0 = &sA[(wv * 2) * 512];
    bf16_t* lA1 = &sA[(wv * 2 + 1) * 512];
    bf16_t* lB0 = &sB[(wv * 2) * 512];
    bf16_t* lB1 = &sB[(wv * 2 + 1) * 512];

    const f32x4 fz = {0.f, 0.f, 0.f, 0.f};
    f32x4 acc[4][4];
#pragma unroll
    for (int i = 0; i < 4; i++)
#pragma unroll
        for (int j = 0; j < 4; j++) acc[i][j] = fz;

    for (int k0 = 0; k0 < K; k0 += 32) {
        gl_lds16(gA, lA0);
        gl_lds16(gA + (size_t)16 * K, lA1);
        gl_lds16(gB, lB0);
        gl_lds16(gB + (size_t)16 * K, lB1);
        gA += 32; gB += 32;
        __syncthreads();

        bf16x8 aF[4], bF[4];
#pragma unroll
        for (int mi = 0; mi < 4; mi++)
            aF[mi] = *(const bf16x8*)(&sA[(wr * 4 + mi) * 512 + (quad * 16 + l16) * 8]);
#pragma unroll
        for (int ni = 0; ni < 4; ni++)
            bF[ni] = *(const bf16x8*)(&sB[(wc * 4 + ni) * 512 + (quad * 16 + l16) * 8]);
#pragma unroll
        for (int mi = 0; mi < 4; mi++)
#pragma unroll
            for (int ni = 0; ni < 4; ni++)
                acc[mi][ni] = __builtin_amdgcn_mfma_f32_16x16x32_bf16(
                    aF[mi], bF[ni], acc[mi][ni], 0, 0, 0);
        __syncthreads();
    }

#pragma unroll
    for (int mi = 0; mi < 4; mi++) {
#pragma unroll
        for (int ni = 0; ni < 4; ni++) {
            int row0 = rowBase + wr * 64 + mi * 16 + quad * 4;
            int col  = colBase + wc * 64 + ni * 16 + l16;
            float bvv = bias[col];
            if (z != 2) {
#pragma unroll
                for (int r = 0; r < 4; r++)
                    Cb[(size_t)(row0 + r) * N + col] = (bf16_t)(acc[mi][ni][r] + bvv);
            } else {
                int b  = row0 >> 11;
                int n0 = row0 & 2047;
                int hh = col >> 7;
                int dd = col & 127;
                bf16x4 p = {(bf16_t)(acc[mi][ni][0] + bvv), (bf16_t)(acc[mi][ni][1] + bvv),
                            (bf16_t)(acc[mi][ni][2] + bvv), (bf16_t)(acc[mi][ni][3] + bvv)};
                *(bf16x4*)(Cb + (size_t)((b * NH + hh) * DHEAD + dd) * NK + n0) = p;
            }
        }
    }
}

// ---------------------------------------------------------------------------
// Wo GEMM (MODE1): Cf = resid + relu(acc + bias).  resid is bf16 LN output.
// ---------------------------------------------------------------------------
__global__ __launch_bounds__(256) void gemm_wo(
    const bf16_t* __restrict__ A, const bf16_t* __restrict__ Bw,
    const float* __restrict__ bias, const bf16_t* resid, float* Cf,
    int M, int N, int K)
{
    const int tid  = threadIdx.x;
    const int lane = tid & 63;
    const int wv   = tid >> 6;
    const int l16  = lane & 15;
    const int quad = (lane >> 4) & 3;
    const int kc4  = lane >> 4;
    const int wr   = wv >> 1, wc = wv & 1;
    const int rowBase = blockIdx.y * 128;
    const int colBase = blockIdx.x * 128;

    __shared__ bf16_t sA[4096];
    __shared__ bf16_t sB[4096];

    const bf16_t* gA = A + (size_t)(rowBase + wv * 32 + l16) * K + kc4 * 8;
    const bf16_t* gB = Bw + (size_t)(colBase + wv * 32 + l16) * K + kc4 * 8;
    bf16_t* lA0 = &sA[(wv * 2) * 512];
    bf16_t* lA1 = &sA[(wv * 2 + 1) * 512];
    bf16_t* lB0 = &sB[(wv * 2) * 512];
    bf16_t* lB1 = &sB[(wv * 2 + 1) * 512];

    const f32x4 fz = {0.f, 0.f, 0.f, 0.f};
    f32x4 acc[4][4];
#pragma unroll
    for (int i = 0; i < 4; i++)
#pragma unroll
        for (int j = 0; j < 4; j++) acc[i][j] = fz;

    for (int k0 = 0; k0 < K; k0 += 32) {
        gl_lds16(gA, lA0);
        gl_lds16(gA + (size_t)16 * K, lA1);
        gl_lds16(gB, lB0);
        gl_lds16(gB + (size_t)16 * K, lB1);
        gA += 32; gB += 32;
        __syncthreads();

        bf16x8 aF[4], bF[4];
#pragma unroll
        for (int mi = 0; mi < 4; mi++)
            aF[mi] = *(const bf16x8*)(&sA[(wr * 4 + mi) * 512 + (quad * 16 + l16) * 8]);
#pragma unroll
        for (int ni = 0; ni < 4; ni++)
            bF[ni] = *(const bf16x8*)(&sB[(wc * 4 + ni) * 512 + (quad * 16 + l16) * 8]);
#pragma unroll
        for (int mi = 0; mi < 4; mi++)
#pragma unroll
            for (int ni = 0; ni < 4; ni++)
                acc[mi][ni] = __builtin_amdgcn_mfma_f32_16x16x32_bf16(
                    aF[mi], bF[ni], acc[mi][ni], 0, 0, 0);
        __syncthreads();
    }

#pragma unroll
    for (int mi = 0; mi < 4; mi++) {
#pragma unroll
        for (int ni = 0; ni < 4; ni++) {
            int row0 = rowBase + wr * 64 + mi * 16 + quad * 4;
            int col  = colBase + wc * 64 + ni * 16 + l16;
            float bvv = bias[col];
#pragma unroll
            for (int r = 0; r < 4; r++) {
                float v = acc[mi][ni][r] + bvv;
                v = v > 0.f ? v : 0.f;
                Cf[(size_t)(row0 + r) * N + col] =
                    (float)resid[(size_t)(row0 + r) * N + col] + v;
            }
        }
    }
}

// ---------------------------------------------------------------------------
// Transposed flash attention: S^T = K Q^T, O^T = V^T P^T.
// v9 = R3/v4 config + two critical-path trims:
//  (a) lane-local defer-max gate: the cross-lane max-reduce (2 shfl, the
//      longest-latency links in the per-iter chain) runs ONLY when some
//      lane's local max exceeds mq+8/SC2 -- wave-uniform branch, rare
//      after tile 0.  Conservative: lane-local max <= true max.
//  (b) O output in bf16 (halves O write + ln0 read traffic).
// 8 waves x 16 q-rows, KVBLK=64 dbuf (64 KB LDS), 4 waves/SIMD.
// ---------------------------------------------------------------------------
__global__ __launch_bounds__(512, 4) void attn_k(
    const bf16_t* __restrict__ qb, const bf16_t* __restrict__ kb,
    const bf16_t* __restrict__ vT, bf16_t* __restrict__ O)
{
    const int tid  = threadIdx.x;
    const int lane = tid & 63;
    const int wv   = tid >> 6;      // 0..7
    const int l16  = lane & 15;
    const int quad = (lane >> 4) & 3;
    const int bh   = blockIdx.x;    // bh-major: same bh -> same XCD
    const int b    = bh >> 3;
    const int h    = bh & 7;
    const int qt   = blockIdx.y * 128;
    const int qrow = b * NQ + qt + wv * 16;   // 16 q-rows per wave
    const int NKT  = NK / 64;       // 32 key-tiles

    __shared__ bf16_t sK[2][8192];  // dbuf: 16 K-frags of 1 KB (64 keys x 128 d)
    __shared__ bf16_t sV[2][8192];  // dbuf: 16 V^T-frags of 1 KB (128 d x 64 k)

    const bf16_t* gKb = kb + ((size_t)b * NK + l16) * DMODEL + h * DHEAD + quad * 8;
    const bf16_t* gVb = vT + ((size_t)bh * DHEAD + l16) * NK + quad * 8;

    // 32 frags/tile-pair, 8 waves: each wave stages 2 K frags + 2 V frags.
    auto stage = [&](int tt, int bufi) {
        const int kt = tt * 64;
#pragma unroll
        for (int j = 0; j < 2; j++) {
            const int f = wv * 2 + j;
            const int kbi = f >> 2, c = f & 3;
            gl_lds16(gKb + (size_t)(kt + kbi * 16) * DMODEL + c * 32,
                     &sK[bufi][f * 512]);
        }
#pragma unroll
        for (int j = 0; j < 2; j++) {
            const int g = wv * 2 + j;
            const int dbi = g >> 1, kc = g & 1;
            gl_lds16(gVb + (size_t)(dbi * 16) * NK + kt + kc * 32,
                     &sV[bufi][g * 512]);
        }
    };

    stage(0, 0);   // prologue prefetch overlaps the Q-fragment loads below

    // Q as B-operand fragments: q = qrow + l16, d = c*32 + quad*8
    bf16x8 qF[4];
#pragma unroll
    for (int c = 0; c < 4; c++)
        qF[c] = *(const bf16x8*)(qb + (size_t)(qrow + l16) * DMODEL +
                                 h * DHEAD + c * 32 + quad * 8);

    const f32x4 fz = {0.f, 0.f, 0.f, 0.f};
    f32x4 accO[8];                // O^T frags per d-block
#pragma unroll
    for (int db = 0; db < 8; db++) accO[db] = fz;
    float mq = -3e38f;
    float lq = 0.f;
    const float SC2 = 0.08838834764831845f * 1.44269504089f;  // log2(e)/sqrt(128)

    const int qa   = (quad & 1) * 2;
    const int srcA = l16 + 16 * qa;
    const int srcB = srcA + 16;
    const bool hi  = (quad >> 1) != 0;

    __syncthreads();              // tile 0 staged (vmcnt drained)
    int cur = 0;

    for (int t = 0; t < NKT; t++) {
        // ---- prefetch next tile into the alternate buffer (no wait here)
        if (t + 1 < NKT) stage(t + 1, cur ^ 1);

        // ---- S^T = K Q^T : A = K frags, B = Q frag
        f32x4 S[4];
        __builtin_amdgcn_s_setprio(1);
#pragma unroll
        for (int kb4 = 0; kb4 < 4; kb4++) {
            S[kb4] = fz;
#pragma unroll
            for (int c = 0; c < 4; c++) {
                bf16x8 kF = *(const bf16x8*)(&sK[cur][(kb4 * 4 + c) * 512 + lane * 8]);
                S[kb4] = __builtin_amdgcn_mfma_f32_16x16x32_bf16(kF, qF[c], S[kb4], 0, 0, 0);
            }
        }
        __builtin_amdgcn_s_setprio(0);

        // ---- online softmax: LANE-LOCAL defer-max gate (no shfl common path)
        float mxl = fmaxf(fmaxf(fmaxf(S[0][0], S[0][1]), fmaxf(S[0][2], S[0][3])),
                    fmaxf(fmaxf(S[1][0], S[1][1]), fmaxf(S[1][2], S[1][3])));
        mxl = fmaxf(mxl, fmaxf(fmaxf(fmaxf(S[2][0], S[2][1]), fmaxf(S[2][2], S[2][3])),
                          fmaxf(fmaxf(S[3][0], S[3][1]), fmaxf(S[3][2], S[3][3]))));
        const bool need = !__all((mxl - mq) * SC2 <= 8.f);
        float al = 1.f;
        if (need) {    // rare: full cross-lane reduce + rescale
            float mx = fmaxf(mxl, __shfl_xor(mxl, 16));
            mx = fmaxf(mx, __shfl_xor(mx, 32));
            float mn = fmaxf(mq, mx);
            al = exp2f((mq - mn) * SC2);
            mq = mn;
        }
        const float mc = mq * SC2;
        float sum = 0.f;
#pragma unroll
        for (int kb4 = 0; kb4 < 4; kb4++)
#pragma unroll
            for (int r = 0; r < 4; r++) {
                float p = exp2f(fmaf(S[kb4][r], SC2, -mc));
                S[kb4][r] = p;
                sum += p;
            }
        lq = lq * al + sum;       // lane-local partial (this lane's 16 keys)
        if (need) {
#pragma unroll
            for (int db = 0; db < 8; db++)
#pragma unroll
                for (int r = 0; r < 4; r++) accO[db][r] *= al;
        }

        // ---- P: pack each C-frag into 2 dwords, shuffle into B-operand frags
        uint2 pk[4];
#pragma unroll
        for (int kb4 = 0; kb4 < 4; kb4++) {
            bf16x4 tt = {(bf16_t)S[kb4][0], (bf16_t)S[kb4][1],
                         (bf16_t)S[kb4][2], (bf16_t)S[kb4][3]};
            pk[kb4] = __builtin_bit_cast(uint2, tt);
        }
        bf16x8 pF[2];
#pragma unroll
        for (int kc = 0; kc < 2; kc++) {
            unsigned a0 = (unsigned)__shfl((int)pk[2 * kc].x, srcA);
            unsigned b0 = (unsigned)__shfl((int)pk[2 * kc + 1].x, srcA);
            unsigned a1 = (unsigned)__shfl((int)pk[2 * kc].y, srcA);
            unsigned b1 = (unsigned)__shfl((int)pk[2 * kc + 1].y, srcA);
            unsigned a2 = (unsigned)__shfl((int)pk[2 * kc].x, srcB);
            unsigned b2 = (unsigned)__shfl((int)pk[2 * kc + 1].x, srcB);
            unsigned a3 = (unsigned)__shfl((int)pk[2 * kc].y, srcB);
            unsigned b3 = (unsigned)__shfl((int)pk[2 * kc + 1].y, srcB);
            uint4 w = {hi ? b0 : a0, hi ? b1 : a1, hi ? b2 : a2, hi ? b3 : a3};
            pF[kc] = __builtin_bit_cast(bf16x8, w);
        }

        // ---- O^T += V^T P^T : A = V^T frags, B = P frag
        __builtin_amdgcn_s_setprio(1);
#pragma unroll
        for (int kc = 0; kc < 2; kc++)
#pragma unroll
            for (int db = 0; db < 8; db++) {
                bf16x8 vF = *(const bf16x8*)(&sV[cur][(db * 2 + kc) * 512 + lane * 8]);
                accO[db] = __builtin_amdgcn_mfma_f32_16x16x32_bf16(vF, pF[kc], accO[db], 0, 0, 0);
            }
        __builtin_amdgcn_s_setprio(0);

        // single barrier per iter: drains the prefetch + releases buffers
        __syncthreads();
        cur ^= 1;
    }

    // finalize denominator (cross-quad partials)
    float s = lq;
    s += __shfl_xor(s, 16);
    s += __shfl_xor(s, 32);
    const float inv = 1.0f / s;

    // O = acc/l + q residual (bf16 out); O^T frag: q=l16, d=db*16+quad*4+r
    const int grow = qrow + l16;
#pragma unroll
    for (int db = 0; db < 8; db++) {
        const int gcol = h * DHEAD + db * 16 + quad * 4;
        bf16x4 qr = *(const bf16x4*)(qb + (size_t)grow * DMODEL + gcol);
        bf16x4 o;
#pragma unroll
        for (int r = 0; r < 4; r++)
            o[r] = (bf16_t)(accO[db][r] * inv + (float)qr[r]);
        *(bf16x4*)(O + (size_t)grow * DMODEL + gcol) = o;
    }
}

// ---------------------------------------------------------------------------
// LayerNorm over rows of 1024, bf16 input -> bf16 output (post-attn LN)
// ---------------------------------------------------------------------------
__global__ __launch_bounds__(256) void lnb_k(
    const bf16_t* __restrict__ X, const float* __restrict__ g,
    const float* __restrict__ bta, bf16_t* __restrict__ Yb)
{
    const int row = blockIdx.x;
    const int t = threadIdx.x;
    bf16x4 xb = *(const bf16x4*)(X + (size_t)row * DMODEL + t * 4);
    float4 x = {(float)xb[0], (float)xb[1], (float)xb[2], (float)xb[3]};
    float s  = x.x + x.y + x.z + x.w;
    float sq = x.x * x.x + x.y * x.y + x.z * x.z + x.w * x.w;
#pragma unroll
    for (int o = 1; o < 64; o <<= 1) {
        s  += __shfl_xor(s, o);
        sq += __shfl_xor(sq, o);
    }
    __shared__ float ls[8];
    int w = t >> 6, ln = t & 63;
    if (ln == 0) { ls[w] = s; ls[4 + w] = sq; }
    __syncthreads();
    s  = ls[0] + ls[1] + ls[2] + ls[3];
    sq = ls[4] + ls[5] + ls[6] + ls[7];
    float mu  = s * (1.f / DMODEL);
    float var = sq * (1.f / DMODEL) - mu * mu;
    float rs  = rsqrtf(var + 1e-5f);
    float4 gv = *(const float4*)(g + t * 4);
    float4 bv = *(const float4*)(bta + t * 4);
    bf16x4 yb = {(bf16_t)((x.x - mu) * rs * gv.x + bv.x),
                 (bf16_t)((x.y - mu) * rs * gv.y + bv.y),
                 (bf16_t)((x.z - mu) * rs * gv.z + bv.z),
                 (bf16_t)((x.w - mu) * rs * gv.w + bv.w)};
    *(bf16x4*)(Yb + (size_t)row * DMODEL + t * 4) = yb;
}

// ---------------------------------------------------------------------------
// LayerNorm over rows of 1024, f32 input (final LN)
// ---------------------------------------------------------------------------
__global__ __launch_bounds__(256) void ln_k(
    const float* __restrict__ X, const float* __restrict__ g,
    const float* __restrict__ bta, float* __restrict__ Yf)
{
    const int row = blockIdx.x;
    const int t = threadIdx.x;
    float4 x = *(const float4*)(X + (size_t)row * DMODEL + t * 4);
    float s  = x.x + x.y + x.z + x.w;
    float sq = x.x * x.x + x.y * x.y + x.z * x.z + x.w * x.w;
#pragma unroll
    for (int o = 1; o < 64; o <<= 1) {
        s  += __shfl_xor(s, o);
        sq += __shfl_xor(sq, o);
    }
    __shared__ float ls[8];
    int w = t >> 6, ln = t & 63;
    if (ln == 0) { ls[w] = s; ls[4 + w] = sq; }
    __syncthreads();
    s  = ls[0] + ls[1] + ls[2] + ls[3];
    sq = ls[4] + ls[5] + ls[6] + ls[7];
    float mu  = s * (1.f / DMODEL);
    float var = sq * (1.f / DMODEL) - mu * mu;
    float rs  = rsqrtf(var + 1e-5f);
    float4 gv = *(const float4*)(g + t * 4);
    float4 bv = *(const float4*)(bta + t * 4);
    float4 y;
    y.x = (x.x - mu) * rs * gv.x + bv.x;
    y.y = (x.y - mu) * rs * gv.y + bv.y;
    y.z = (x.z - mu) * rs * gv.z + bv.z;
    y.w = (x.w - mu) * rs * gv.w + bv.w;
    *(float4*)(Yf + (size_t)row * DMODEL + t * 4) = y;
}

// ---------------------------------------------------------------------------
extern "C" void kernel_launch(void* const* d_in, const int* in_sizes, int n_in,
                              void* d_out, int out_size, void* d_ws, size_t ws_size,
                              hipStream_t stream)
{
    const float* Q  = (const float*)d_in[0];
    const float* Kx = (const float*)d_in[1];
    const float* Wq = (const float*)d_in[2];
    const float* bq = (const float*)d_in[3];
    const float* Wk = (const float*)d_in[4];
    const float* bk = (const float*)d_in[5];
    const float* Wv = (const float*)d_in[6];
    const float* bv = (const float*)d_in[7];
    const float* Wo = (const float*)d_in[8];
    const float* bo = (const float*)d_in[9];
    const float* g0 = (const float*)d_in[10];
    const float* b0 = (const float*)d_in[11];
    const float* g1 = (const float*)d_in[12];
    const float* b1 = (const float*)d_in[13];
    float* out = (float*)d_out;

    char* ws = (char*)d_ws;
    bf16_t* Qc  = (bf16_t*)(ws);                  // 16,777,216
    bf16_t* Kc  = (bf16_t*)(ws + 16777216);       // 16,777,216
    bf16_t* Wqc = (bf16_t*)(ws + 33554432);       // 2,097,152
    bf16_t* Wkc = (bf16_t*)(ws + 35651584);
    bf16_t* Wvc = (bf16_t*)(ws + 37748736);
    bf16_t* Woc = (bf16_t*)(ws + 39845888);
    bf16_t* qbb = (bf16_t*)(ws + 41943040);       // 16,777,216
    bf16_t* kbb = (bf16_t*)(ws + 58720256);       // 16,777,216
    bf16_t* vT  = (bf16_t*)(ws + 75497472);       // 16,777,216
    bf16_t* Obuf = (bf16_t*)(ws + 92274688);      // 16,777,216 (bf16 attn out)
    float*  Lf  = (float*)(ws);                   // alias Qc+Kc (dead after proj)
    bf16_t* Lb  = kbb;                            // alias kbb (dead after attn)

    CvtArgs ca;
    ca.s[0] = Q;  ca.d[0] = Qc;  ca.n[0] = B_DIM * NQ * DMODEL;
    ca.s[1] = Kx; ca.d[1] = Kc;  ca.n[1] = B_DIM * NK * DMODEL;
    ca.s[2] = Wq; ca.d[2] = Wqc; ca.n[2] = DMODEL * DMODEL;
    ca.s[3] = Wk; ca.d[3] = Wkc; ca.n[3] = DMODEL * DMODEL;
    ca.s[4] = Wv; ca.d[4] = Wvc; ca.n[4] = DMODEL * DMODEL;
    ca.s[5] = Wo; ca.d[5] = Woc; ca.n[5] = DMODEL * DMODEL;
    cvt_k<<<dim3(512, 6), 256, 0, stream>>>(ca);

    const int M = B_DIM * NQ;  // 8192

    proj_k<<<dim3(DMODEL / 128, M / 128, 3), 256, 0, stream>>>(
        Qc, Kc, Wqc, Wkc, Wvc, bq, bk, bv, qbb, kbb, vT);

    attn_k<<<dim3(B_DIM * NH, NQ / 128), 512, 0, stream>>>(qbb, kbb, vT, Obuf);

    // ln0: bf16 in -> bf16 out (gemm_wo reads resid as bf16)
    lnb_k<<<dim3(M), 256, 0, stream>>>(Obuf, g0, b0, Lb);

    gemm_wo<<<dim3(DMODEL / 128, M / 128), 256, 0, stream>>>(
        Lb, Woc, bo, Lb, Lf, M, DMODEL, DMODEL);

    ln_k<<<dim3(M), 256, 0, stream>>>(Lf, g1, b1, out);
}